// Round 6
// baseline (191.061 us; speedup 1.0000x reference)
//
#include <hip/hip_runtime.h>
#include <hip/hip_cooperative_groups.h>
#include <math.h>

namespace cg = cooperative_groups;

#define BB 16
#define NN 2048
#define LOG2E 1.4426950408889634f
#define LN2   0.6931471805599453f
#define NSL 8                      // j-slices (tile 256)
#define NIC 4                      // i-chunks of 512 (2 rows/thread)
#define NBLK (NIC * NSL * BB)      // 512 blocks = 2 per CU

// ws layout (float offsets); all written-before-read each call, no zero-init
#define OFF_E  0                         // [NSL][BB*NN] E partials (1 MB)
#define OFF_P  (NSL * BB * NN)           // [512] pairwise block partials
#define OFF_LL (OFF_P + NBLK)            // [BB] per-row N*ll
#define OFF_PS (OFF_LL + BB)             // [1] total pairwise sum

// ---------- Single cooperative kernel: O(N^2) sweep + reductions + combine ----------
// Phase 1: full N x N sweep; each unordered pair visited twice with identical
//   sign-folded softplus value; diagonal contributes exactly log2(2)=1 per
//   element. Log2 domain: P = mp*log2e.
//   softplus_nat total = LN2*( (sum_xd + sum_|d|)/2 + sum log2(1+2^-|d|) ),
//   sum_xd = (256*Pi - sum P_tile) - 2*sum_{winner} d; log batched over 16
//   pairs via product of (1+e2) (each factor in [1,2], 16 factors < 2^16: safe).
// Phase 2 (after grid sync): blocks 0..15 reduce E slices -> per-row N*ll;
//   block 16 reduces the 512 pairwise partials.
// Phase 3 (after grid sync): block 0 combines -> out.
__global__ __launch_bounds__(256, 2) void fused_all(
    const float* __restrict__ pred, const float* __restrict__ tru,
    const float* __restrict__ masks, const float* __restrict__ lbl,
    float* __restrict__ ws, float* __restrict__ out) {
  const int bid = blockIdx.x;
  const int ic = bid & 3;            // 0..3  i-tile of 512
  const int jc = (bid >> 2) & 7;     // 0..7  j-tile of 256
  const int b  = bid >> 5;           // 0..15
  const int tid = threadIdx.x;

  __shared__ float4 tile[256];       // {t_j, P_j, e_j, 0}
  __shared__ float wred[4];

  // ---- Phase 1 ----
  {
    int j = b * NN + jc * 256 + tid;
    float m = masks[j];
    float t = tru[j] * m;
    float P = pred[j] * m * LOG2E;
    tile[tid] = make_float4(t, P, __builtin_amdgcn_exp2f(P), 0.f);
  }

  float ti[2], Pi[2], sWD[2], sAB[2], sLG[2], Ee[2];
  #pragma unroll
  for (int k = 0; k < 2; ++k) {
    int i = b * NN + ic * 512 + k * 256 + tid;
    float m = masks[i];
    ti[k] = tru[i] * m;
    Pi[k] = pred[i] * m * LOG2E;
    sWD[k] = 0.f; sAB[k] = 0.f; sLG[k] = 0.f; Ee[k] = 0.f;
  }
  __syncthreads();

  float Stile;
  {
    float v = tile[tid].y;
    #pragma unroll
    for (int off = 32; off >= 1; off >>= 1) v += __shfl_down(v, off);
    if ((tid & 63) == 0) wred[tid >> 6] = v;
    __syncthreads();
    Stile = (wred[0] + wred[1]) + (wred[2] + wred[3]);
  }

  for (int jo = 0; jo < 256; jo += 16) {
    float pr0 = 1.f, pr1 = 1.f;
    #pragma unroll
    for (int q = 0; q < 16; ++q) {
      float4 v = tile[jo + q];       // broadcast ds_read_b128, feeds 2 pairs
      {
        float d = Pi[0] - v.y;
        bool w = (v.x < ti[0]);
        sWD[0] += w ? d : 0.f;
        sAB[0] += fabsf(d);
        float e2 = __builtin_amdgcn_exp2f(-fabsf(d));
        pr0 *= (1.f + e2);
        Ee[0] += w ? v.z : 0.f;
      }
      {
        float d = Pi[1] - v.y;
        bool w = (v.x < ti[1]);
        sWD[1] += w ? d : 0.f;
        sAB[1] += fabsf(d);
        float e2 = __builtin_amdgcn_exp2f(-fabsf(d));
        pr1 *= (1.f + e2);
        Ee[1] += w ? v.z : 0.f;
      }
    }
    sLG[0] += __builtin_amdgcn_logf(pr0);   // log2
    sLG[1] += __builtin_amdgcn_logf(pr1);
  }

  #pragma unroll
  for (int k = 0; k < 2; ++k) {
    int i = ic * 512 + k * 256 + tid;
    ws[OFF_E + jc * (BB * NN) + b * NN + i] = Ee[k];
  }

  float pp = 0.f;
  #pragma unroll
  for (int k = 0; k < 2; ++k) {
    float sXD = (256.f * Pi[k] - Stile) - 2.f * sWD[k];
    pp += (sXD + sAB[k]) * 0.5f + sLG[k];
  }
  #pragma unroll
  for (int off = 32; off >= 1; off >>= 1) pp += __shfl_down(pp, off);
  __syncthreads();
  if ((tid & 63) == 0) wred[tid >> 6] = pp;
  __syncthreads();
  if (tid == 0) ws[OFF_P + bid] = (wred[0] + wred[1]) + (wred[2] + wred[3]);

  __threadfence();          // device-scope: make ws stores visible cross-XCD
  cg::this_grid().sync();

  // ---- Phase 2 ----
  if (bid < BB) {
    const int base = bid * NN + tid * 8;
    const float4* p4 = (const float4*)(pred + base);
    const float4* m4 = (const float4*)(masks + base);
    float4 pa = p4[0], pb = p4[1];
    float4 ma = m4[0], mb = m4[1];
    float mp[8] = {pa.x * ma.x, pa.y * ma.y, pa.z * ma.z, pa.w * ma.w,
                   pb.x * mb.x, pb.y * mb.y, pb.z * mb.z, pb.w * mb.w};
    float Et[8];
    #pragma unroll
    for (int q = 0; q < 8; ++q)
      Et[q] = __builtin_amdgcn_exp2f(mp[q] * LOG2E);   // own term (j==i)
    #pragma unroll
    for (int s = 0; s < NSL; ++s) {
      const float4* e4 = (const float4*)(ws + OFF_E + s * (BB * NN) + base);
      float4 ea = e4[0], eb = e4[1];
      Et[0] += ea.x; Et[1] += ea.y; Et[2] += ea.z; Et[3] += ea.w;
      Et[4] += eb.x; Et[5] += eb.y; Et[6] += eb.z; Et[7] += eb.w;
    }
    float sP = 0.f, sL = 0.f;
    #pragma unroll
    for (int q = 0; q < 8; ++q) {
      sP += mp[q];
      sL += __builtin_amdgcn_logf(Et[q]);   // log2(E_i)
    }
    float r = sP - LN2 * sL;                // row partial of N*ll_b
    #pragma unroll
    for (int off = 32; off >= 1; off >>= 1) r += __shfl_down(r, off);
    __syncthreads();
    if ((tid & 63) == 0) wred[tid >> 6] = r;
    __syncthreads();
    if (tid == 0) ws[OFF_LL + bid] = (wred[0] + wred[1]) + (wred[2] + wred[3]);
  } else if (bid == BB) {
    float s = ws[OFF_P + tid] + ws[OFF_P + 256 + tid];
    #pragma unroll
    for (int off = 32; off >= 1; off >>= 1) s += __shfl_down(s, off);
    __syncthreads();
    if ((tid & 63) == 0) wred[tid >> 6] = s;
    __syncthreads();
    if (tid == 0) ws[OFF_PS] = (wred[0] + wred[1]) + (wred[2] + wred[3]);
  }

  __threadfence();
  cg::this_grid().sync();

  // ---- Phase 3 ----
  if (bid == 0 && tid == 0) {
    float ll = 0.f;
    #pragma unroll
    for (int k = 0; k < BB; ++k) ll += ws[OFF_LL + k];
    float PS = ws[OFF_PS];
    float ranking = -ll / ((float)BB * (float)NN);
    // PS = 2*sum_ref(log2-units) + B*N (diagonal gives log2(2)=1 each)
    float pairwise = LN2 * (PS - (float)(BB * NN)) /
                     ((float)BB * (float)NN * (float)(NN - 1));
    out[0] = ranking + 0.3f * pairwise + 0.03f * lbl[0];
  }
}

extern "C" void kernel_launch(void* const* d_in, const int* in_sizes, int n_in,
                              void* d_out, int out_size, void* d_ws, size_t ws_size,
                              hipStream_t stream) {
  const float* y_pred = (const float*)d_in[0];
  const float* y_true = (const float*)d_in[1];
  const float* masks  = (const float*)d_in[2];
  const float* lbl    = (const float*)d_in[3];
  float* out = (float*)d_out;
  float* ws = (float*)d_ws;

  void* args[] = {(void*)&y_pred, (void*)&y_true, (void*)&masks,
                  (void*)&lbl, (void*)&ws, (void*)&out};
  hipLaunchCooperativeKernel((void*)fused_all, dim3(NBLK), dim3(256),
                             args, 0, stream);
}

// Round 7
// 31.592 us; speedup vs baseline: 6.0478x; 6.0478x over previous
//
#include <hip/hip_runtime.h>
#include <hip/hip_bf16.h>
#include <math.h>

#define BB 16
#define NN 2048
#define LOG2E 1.4426950408889634f
#define LN2   0.6931471805599453f
#define NSL 16         // j-slices (tile 128)
#define NIC 2          // i-chunks of 1024 (4 rows per thread)
#define NBLK (NIC * NSL * BB)   // 512 blocks = 2 per CU

// ws layout (float offsets); all written-before-read each call, no zero-init.
#define OFF_E   0                        // [NSL][BB*NN] E partials (2 MB)
#define OFF_P   (NSL * BB * NN)          // [512] pairwise block partials
#define OFF_LL  (OFF_P + NBLK)           // [BB] per-row N*ll
#define OFF_PS  (OFF_LL + BB)            // [1] total pairwise sum
#define OFF_CNT (OFF_PS + 1)             // [1] K2 completion counter (u32)

// ---------- K1: fused O(N^2) sweep (pairwise softplus + rank-E partials) ----------
// Full N x N sweep; each unordered pair visited twice with the identical
// sign-folded value; diagonal contributes exactly log2(2)=1 per element
// (both corrected analytically in the finalize). Log2 domain: P = mp*log2e.
// softplus_nat total = LN2*( (sum_xd + sum_|d|)/2 + sum log2(1+2^-|d|) ),
// sum_xd = (128*Pi - sum P_tile) - 2*sum_{winner} d. Logs batched over 16
// pairs via prod of (1+e2) (factors in [1,2], 16 of them < 2^16: exact-safe).
// 4 i-rows per thread: one broadcast ds_read_b128 feeds 4 pair-computations
// (LDS pipe demand ~55% of issue, VALU-bound).
// K1 also zeroes the K2 counter (stream order makes this safe).
__global__ __launch_bounds__(256, 2) void k1_sweep(
    const float* __restrict__ pred, const float* __restrict__ tru,
    const float* __restrict__ masks, float* __restrict__ ws) {
  const int ic = blockIdx.x;   // 0..1   i-tile of 1024 (4 rows/thread)
  const int jc = blockIdx.y;   // 0..15  j-tile of 128
  const int b  = blockIdx.z;   // 0..15
  const int tid = threadIdx.x;

  __shared__ float4 tile[128];   // {t_j, P_j, e_j, 0}
  __shared__ float wred[4];

  if (tid < 128) {
    int j = b * NN + jc * 128 + tid;
    float m = masks[j];
    float t = tru[j] * m;
    float P = pred[j] * m * LOG2E;
    tile[tid] = make_float4(t, P, __builtin_amdgcn_exp2f(P), 0.f);
  }

  float ti[4], Pi[4], sWD[4], sAB[4], sLG[4], Ee[4];
  #pragma unroll
  for (int k = 0; k < 4; ++k) {
    int i = b * NN + ic * 1024 + k * 256 + tid;
    float m = masks[i];
    ti[k] = tru[i] * m;
    Pi[k] = pred[i] * m * LOG2E;
    sWD[k] = 0.f; sAB[k] = 0.f; sLG[k] = 0.f; Ee[k] = 0.f;
  }
  __syncthreads();

  // block-uniform sum of P over the 128-tile (each element read twice -> *0.5)
  float Stile;
  {
    float v = tile[tid & 127].y;
    #pragma unroll
    for (int off = 32; off >= 1; off >>= 1) v += __shfl_down(v, off);
    if ((tid & 63) == 0) wred[tid >> 6] = v;
    __syncthreads();
    Stile = ((wred[0] + wred[1]) + (wred[2] + wred[3])) * 0.5f;
  }

  for (int jo = 0; jo < 128; jo += 16) {
    float pr[4] = {1.f, 1.f, 1.f, 1.f};
    #pragma unroll
    for (int q = 0; q < 16; ++q) {
      float4 v = tile[jo + q];           // one broadcast b128 feeds 4 pairs
      #pragma unroll
      for (int k = 0; k < 4; ++k) {
        float d = Pi[k] - v.y;
        bool w = (v.x < ti[k]);          // t_i > t_j
        sWD[k] += w ? d : 0.f;
        sAB[k] += fabsf(d);
        float e2 = __builtin_amdgcn_exp2f(-fabsf(d));
        pr[k] = __builtin_fmaf(e2, pr[k], pr[k]);   // pr *= (1+e2)
        Ee[k] += w ? v.z : 0.f;
      }
    }
    #pragma unroll
    for (int k = 0; k < 4; ++k)
      sLG[k] += __builtin_amdgcn_logf(pr[k]);   // log2
  }

  // E partials: plain stores, slice-major (no atomics, no pre-zero)
  #pragma unroll
  for (int k = 0; k < 4; ++k) {
    int i = ic * 1024 + k * 256 + tid;
    ws[OFF_E + jc * (BB * NN) + b * NN + i] = Ee[k];
  }

  float pp = 0.f;
  #pragma unroll
  for (int k = 0; k < 4; ++k) {
    float sXD = (128.f * Pi[k] - Stile) - 2.f * sWD[k];
    pp += (sXD + sAB[k]) * 0.5f + sLG[k];
  }
  #pragma unroll
  for (int off = 32; off >= 1; off >>= 1) pp += __shfl_down(pp, off);
  __syncthreads();
  if ((tid & 63) == 0) wred[tid >> 6] = pp;
  __syncthreads();
  const int bid = blockIdx.x + NIC * (blockIdx.y + NSL * blockIdx.z);
  if (tid == 0) {
    ws[OFF_P + bid] = (wred[0] + wred[1]) + (wred[2] + wred[3]);
    if (bid == 0) ((unsigned int*)ws)[OFF_CNT] = 0u;   // reset K2 counter
  }
}

// ---------- K2: reductions + last-block finalize ----------
__global__ __launch_bounds__(256) void k2_reduce(
    const float* __restrict__ pred, const float* __restrict__ masks,
    const float* __restrict__ lbl, float* __restrict__ ws,
    float* __restrict__ out) {
  const int bid = blockIdx.x;   // 0..16
  const int tid = threadIdx.x;
  __shared__ float wred[4];

  if (bid < BB) {
    // per-row E reduction -> N*ll partial
    const int base = bid * NN + tid * 8;
    const float4* p4 = (const float4*)(pred + base);
    const float4* m4 = (const float4*)(masks + base);
    float4 pa = p4[0], pb = p4[1];
    float4 ma = m4[0], mb = m4[1];
    float mp[8] = {pa.x * ma.x, pa.y * ma.y, pa.z * ma.z, pa.w * ma.w,
                   pb.x * mb.x, pb.y * mb.y, pb.z * mb.z, pb.w * mb.w};
    float Et[8];
    #pragma unroll
    for (int q = 0; q < 8; ++q)
      Et[q] = __builtin_amdgcn_exp2f(mp[q] * LOG2E);   // own term (j==i)
    #pragma unroll
    for (int s = 0; s < NSL; ++s) {
      const float4* e4 = (const float4*)(ws + OFF_E + s * (BB * NN) + base);
      float4 ea = e4[0], eb = e4[1];
      Et[0] += ea.x; Et[1] += ea.y; Et[2] += ea.z; Et[3] += ea.w;
      Et[4] += eb.x; Et[5] += eb.y; Et[6] += eb.z; Et[7] += eb.w;
    }
    float sP = 0.f, sL = 0.f;
    #pragma unroll
    for (int q = 0; q < 8; ++q) {
      sP += mp[q];
      sL += __builtin_amdgcn_logf(Et[q]);   // log2(E_i)
    }
    float r = sP - LN2 * sL;
    #pragma unroll
    for (int off = 32; off >= 1; off >>= 1) r += __shfl_down(r, off);
    if ((tid & 63) == 0) wred[tid >> 6] = r;
    __syncthreads();
    if (tid == 0) ws[OFF_LL + bid] = (wred[0] + wred[1]) + (wred[2] + wred[3]);
  } else {
    // pairwise partial reduction (512 -> 1)
    float s = ws[OFF_P + tid] + ws[OFF_P + 256 + tid];
    #pragma unroll
    for (int off = 32; off >= 1; off >>= 1) s += __shfl_down(s, off);
    if ((tid & 63) == 0) wred[tid >> 6] = s;
    __syncthreads();
    if (tid == 0) ws[OFF_PS] = (wred[0] + wred[1]) + (wred[2] + wred[3]);
  }

  // last block to finish performs the combine
  if (tid == 0) {
    __threadfence();   // release our result
    unsigned int old = atomicAdd(&((unsigned int*)ws)[OFF_CNT], 1u);
    if (old == BB) {   // 17th (last) arriver
      __threadfence(); // acquire all results
      float ll = 0.f;
      #pragma unroll
      for (int k = 0; k < BB; ++k) ll += ws[OFF_LL + k];
      float PS = ws[OFF_PS];
      float ranking = -ll / ((float)BB * (float)NN);
      // PS = 2*sum_ref(log2-units) + B*N (diagonal gives log2(2)=1 each)
      float pairwise = LN2 * (PS - (float)(BB * NN)) /
                       ((float)BB * (float)NN * (float)(NN - 1));
      out[0] = ranking + 0.3f * pairwise + 0.03f * lbl[0];
    }
  }
}

extern "C" void kernel_launch(void* const* d_in, const int* in_sizes, int n_in,
                              void* d_out, int out_size, void* d_ws, size_t ws_size,
                              hipStream_t stream) {
  const float* y_pred = (const float*)d_in[0];
  const float* y_true = (const float*)d_in[1];
  const float* masks  = (const float*)d_in[2];
  const float* lbl    = (const float*)d_in[3];
  float* out = (float*)d_out;
  float* ws = (float*)d_ws;

  k1_sweep<<<dim3(NIC, NSL, BB), 256, 0, stream>>>(y_pred, y_true, masks, ws);
  k2_reduce<<<BB + 1, 256, 0, stream>>>(y_pred, masks, lbl, ws, out);
}

// Round 8
// 24.942 us; speedup vs baseline: 7.6601x; 1.2666x over previous
//
#include <hip/hip_runtime.h>
#include <hip/hip_bf16.h>
#include <math.h>

#define BB 16
#define NN 2048
#define LOG2E 1.4426950408889634f
#define LN2   0.6931471805599453f

// E-sweep role: full N x N, j-tiles of 256, 4 i-rows/thread
#define E_NIC 2                         // i-chunks of 1024
#define E_NSL 8                         // j-slices of 256
#define E_NBLK (E_NIC * E_NSL * BB)     // 256 blocks

// pairwise role: triangular 8x8 grid of 256x256 tiles per row
#define P_NT 36                         // 28 offdiag + 8 diag
#define P_NBLK (P_NT * BB)              // 576 blocks
// diag tiles at tt = 0,8,15,21,26,30,33,35
#define DIAGMASK 0xA44208101ull

#define NBLK_TOT (E_NBLK + P_NBLK)      // 832 blocks

// ws float offsets; everything written-before-read each call, no zero-init
#define OFF_E   0                        // [E_NSL][BB*NN] E partials (1 MB)
#define OFF_PO  (E_NSL * BB * NN)        // [576] pairwise tile partials
#define OFF_LL  (OFF_PO + P_NBLK)        // [BB] per-row N*ll
#define OFF_PS  (OFF_LL + BB)            // [1] weighted pairwise sum
#define OFF_CNT (OFF_PS + 2)             // [1] finalize counter (u32)

// ---------- KA: one dispatch, two roles ----------
// E role (bid<256): E_i partials = sum_{t_j<t_i} e_j over a 256-j slice.
// Pairwise role: triangular tiles; per unordered pair ONE visit (offdiag) or
// the double-visit fold (diag tiles, weight 0.5 + self-correction in K2).
// Log2 domain: P = mp*log2e. softplus_nat total over a tile-thread =
// LN2*( (sXD + sAB)/2 + sLG ), sXD = 256*Pi - Stile - 2*sum_{winner} d.
// Logs batched: prod of (1+e2) over 32 pairs (factors in [1,2] -> < 2^32, safe).
__global__ __launch_bounds__(256) void ka_sweep(
    const float* __restrict__ pred, const float* __restrict__ tru,
    const float* __restrict__ masks, float* __restrict__ ws) {
  const int bid = blockIdx.x;
  const int tid = threadIdx.x;
  __shared__ float4 tile[128];
  __shared__ float wred[4];

  if (bid < E_NBLK) {
    // ----- E role -----
    const int ic = bid & (E_NIC - 1);
    const int jc = (bid >> 1) & (E_NSL - 1);
    const int b  = bid >> 4;
    if (tid < 128) {
      int jg = b * NN + jc * 256 + 2 * tid;
      float2 tv = *(const float2*)(tru + jg);
      float2 pv = *(const float2*)(pred + jg);
      float2 mv = *(const float2*)(masks + jg);
      float P0 = pv.x * mv.x * LOG2E;
      float P1 = pv.y * mv.y * LOG2E;
      tile[tid] = make_float4(tv.x * mv.x, __builtin_amdgcn_exp2f(P0),
                              tv.y * mv.y, __builtin_amdgcn_exp2f(P1));
    }
    float ti[4], Ee[4];
    #pragma unroll
    for (int k = 0; k < 4; ++k) {
      int i = b * NN + ic * 1024 + k * 256 + tid;
      ti[k] = tru[i] * masks[i];
      Ee[k] = 0.f;
    }
    __syncthreads();
    #pragma unroll 8
    for (int jj = 0; jj < 128; ++jj) {
      float4 v = tile[jj];                 // {t0,e0,t1,e1}: 1 b128 per 8 pairs
      #pragma unroll
      for (int k = 0; k < 4; ++k) {
        Ee[k] += (v.x < ti[k]) ? v.y : 0.f;
        Ee[k] += (v.z < ti[k]) ? v.w : 0.f;
      }
    }
    #pragma unroll
    for (int k = 0; k < 4; ++k) {
      int i = ic * 1024 + k * 256 + tid;
      ws[OFF_E + jc * (BB * NN) + b * NN + i] = Ee[k];
    }
    if (bid == 0 && tid == 0) ((unsigned int*)ws)[OFF_CNT] = 0u;
  } else {
    // ----- pairwise role -----
    const int pb = bid - E_NBLK;
    const int b = pb / P_NT;
    int tt = pb - b * P_NT;
    int ic = 0, rem = tt, span = 8;
    while (rem >= span) { rem -= span; ++ic; --span; }
    const int jc = ic + rem;

    if (tid < 128) {
      int jg = b * NN + jc * 256 + 2 * tid;
      float2 tv = *(const float2*)(tru + jg);
      float2 pv = *(const float2*)(pred + jg);
      float2 mv = *(const float2*)(masks + jg);
      tile[tid] = make_float4(tv.x * mv.x, pv.x * mv.x * LOG2E,
                              tv.y * mv.y, pv.y * mv.y * LOG2E);
    }
    const int i = b * NN + ic * 256 + tid;
    const float mi = masks[i];
    const float ti = tru[i] * mi;
    const float Pi = pred[i] * mi * LOG2E;
    __syncthreads();

    // Stile = sum of P over the 256-j tile (each entry read twice -> *0.5)
    float Stile;
    {
      float4 v = tile[tid & 127];
      float sv = v.y + v.w;
      #pragma unroll
      for (int off = 32; off >= 1; off >>= 1) sv += __shfl_down(sv, off);
      if ((tid & 63) == 0) wred[tid >> 6] = sv;
      __syncthreads();
      Stile = ((wred[0] + wred[1]) + (wred[2] + wred[3])) * 0.5f;
    }

    float sWD = 0.f, sAB = 0.f, sLG = 0.f;
    for (int jo = 0; jo < 128; jo += 16) {
      float pr = 1.f;
      #pragma unroll
      for (int q = 0; q < 16; ++q) {
        float4 v = tile[jo + q];           // {t0,P0,t1,P1}: 1 b128 per 2 pairs
        float dA = Pi - v.y;
        sWD += (v.x < ti) ? dA : 0.f;
        sAB += fabsf(dA);
        pr = __builtin_fmaf(__builtin_amdgcn_exp2f(-fabsf(dA)), pr, pr);
        float dB = Pi - v.w;
        sWD += (v.z < ti) ? dB : 0.f;
        sAB += fabsf(dB);
        pr = __builtin_fmaf(__builtin_amdgcn_exp2f(-fabsf(dB)), pr, pr);
      }
      sLG += __builtin_amdgcn_logf(pr);    // log2, amortized over 32 pairs
    }
    float sXD = (256.f * Pi - Stile) - 2.f * sWD;
    float pp = (sXD + sAB) * 0.5f + sLG;
    #pragma unroll
    for (int off = 32; off >= 1; off >>= 1) pp += __shfl_down(pp, off);
    __syncthreads();
    if ((tid & 63) == 0) wred[tid >> 6] = pp;
    __syncthreads();
    if (tid == 0) ws[OFF_PO + pb] = (wred[0] + wred[1]) + (wred[2] + wred[3]);
  }
}

// ---------- K2: reductions + last-block finalize ----------
__global__ __launch_bounds__(256) void k2_reduce(
    const float* __restrict__ pred, const float* __restrict__ masks,
    const float* __restrict__ lbl, float* __restrict__ ws,
    float* __restrict__ out) {
  const int bid = blockIdx.x;   // 0..16
  const int tid = threadIdx.x;
  __shared__ float wred[4];

  if (bid < BB) {
    // per-row E reduction -> N*ll partial
    const int base = bid * NN + tid * 8;
    const float4* p4 = (const float4*)(pred + base);
    const float4* m4 = (const float4*)(masks + base);
    float4 pa = p4[0], pb = p4[1];
    float4 ma = m4[0], mb = m4[1];
    float mp[8] = {pa.x * ma.x, pa.y * ma.y, pa.z * ma.z, pa.w * ma.w,
                   pb.x * mb.x, pb.y * mb.y, pb.z * mb.z, pb.w * mb.w};
    float Et[8];
    #pragma unroll
    for (int q = 0; q < 8; ++q)
      Et[q] = __builtin_amdgcn_exp2f(mp[q] * LOG2E);   // own term (j==i)
    #pragma unroll
    for (int s = 0; s < E_NSL; ++s) {
      const float4* e4 = (const float4*)(ws + OFF_E + s * (BB * NN) + base);
      float4 ea = e4[0], eb = e4[1];
      Et[0] += ea.x; Et[1] += ea.y; Et[2] += ea.z; Et[3] += ea.w;
      Et[4] += eb.x; Et[5] += eb.y; Et[6] += eb.z; Et[7] += eb.w;
    }
    float sP = 0.f, sL = 0.f;
    #pragma unroll
    for (int q = 0; q < 8; ++q) {
      sP += mp[q];
      sL += __builtin_amdgcn_logf(Et[q]);   // log2(E_i)
    }
    float r = sP - LN2 * sL;
    #pragma unroll
    for (int off = 32; off >= 1; off >>= 1) r += __shfl_down(r, off);
    if ((tid & 63) == 0) wred[tid >> 6] = r;
    __syncthreads();
    if (tid == 0) ws[OFF_LL + bid] = (wred[0] + wred[1]) + (wred[2] + wred[3]);
  } else {
    // weighted pairwise partial reduction (576 -> 1); diag tiles weight 0.5
    float s = 0.f;
    for (int pb = tid; pb < P_NBLK; pb += 256) {
      int tt = pb % P_NT;
      float w = ((DIAGMASK >> tt) & 1ull) ? 0.5f : 1.0f;
      s += w * ws[OFF_PO + pb];
    }
    #pragma unroll
    for (int off = 32; off >= 1; off >>= 1) s += __shfl_down(s, off);
    if ((tid & 63) == 0) wred[tid >> 6] = s;
    __syncthreads();
    if (tid == 0) ws[OFF_PS] = (wred[0] + wred[1]) + (wred[2] + wred[3]);
  }

  // last block to finish performs the combine
  if (tid == 0) {
    __threadfence();   // release our result
    unsigned int old = atomicAdd(&((unsigned int*)ws)[OFF_CNT], 1u);
    if (old == BB) {   // 17th (last) arriver
      __threadfence(); // acquire all results
      float ll = 0.f;
      #pragma unroll
      for (int k = 0; k < BB; ++k) ll += ws[OFF_LL + k];
      float PSw = ws[OFF_PS];
      float ranking = -ll / ((float)BB * (float)NN);
      // PSw = S_true(log2) + 0.5*B*N (diag self-pairs contribute 1.0 each,
      // diag tiles double-visit at weight 0.5)
      float pairwise = LN2 * (PSw - 0.5f * (float)(BB * NN)) * 2.0f /
                       ((float)BB * (float)NN * (float)(NN - 1));
      out[0] = ranking + 0.3f * pairwise + 0.03f * lbl[0];
    }
  }
}

extern "C" void kernel_launch(void* const* d_in, const int* in_sizes, int n_in,
                              void* d_out, int out_size, void* d_ws, size_t ws_size,
                              hipStream_t stream) {
  const float* y_pred = (const float*)d_in[0];
  const float* y_true = (const float*)d_in[1];
  const float* masks  = (const float*)d_in[2];
  const float* lbl    = (const float*)d_in[3];
  float* out = (float*)d_out;
  float* ws = (float*)d_ws;

  ka_sweep<<<NBLK_TOT, 256, 0, stream>>>(y_pred, y_true, masks, ws);
  k2_reduce<<<BB + 1, 256, 0, stream>>>(y_pred, masks, lbl, ws, out);
}